// Round 4
// baseline (71.337 us; speedup 1.0000x reference)
//
#include <hip/hip_runtime.h>
#include <hip/hip_bf16.h>
#include <math.h>

#define NN 128   // nodes (C_OUT)
#define ND 40    // node_dim
#define BB 32    // batch
#define CC 64    // channels
#define LL 64    // length
#define GDIM (CC*LL)  // 4096

typedef __attribute__((ext_vector_type(8))) short bf16x8;
typedef __attribute__((ext_vector_type(16))) float f32x16;

static __device__ __forceinline__ unsigned pk2(float a, float b) {
    __hip_bfloat162 h;
    h.x = __float2bfloat16(a);
    h.y = __float2bfloat16(b);
    return *(unsigned*)&h;
}
static __device__ __forceinline__ float bl(unsigned u) { return __uint_as_float(u << 16); }
static __device__ __forceinline__ float bh(unsigned u) { return __uint_as_float(u & 0xffff0000u); }

// tanh-form GELU via sigmoid: 0.5v(1+tanh(c(v+a v^3))) = v*sigmoid(2c(v+a v^3))
// overflow-safe: exp(-big)->0 => g=v ; exp(+big)->inf => rcp->0 => g=0.
static __device__ __forceinline__ float gelu(float v) {
    float v2 = v * v;
    float zn = v * fmaf(v2, -0.07135481627f, -1.5957691216f);  // -2c(1 + a v^2)
    float e  = __expf(zn);
    return v * __builtin_amdgcn_rcpf(1.f + e);
}

// ---------------------------------------------------------------------------
// Single prep kernel: 64 blocks x 256 threads; block i computes M rows 2i,2i+1.
// Phase A (redundant per block): A = rownorm(softmax(relu(nv1@nv2)) + I) in LDS.
// Phase t: t[u] = sum_w W2[o,w] A[w,u];  c[w] = 0.5 W1 + 0.25 W2 + 0.25 t.
// Phase M: M[o,v] = (W0+.5W1+.5W2)[o,v] + sum_w c[w] A[w,v]  -> Mfrag (bf16,
//   MFMA-A-fragment layout for k_main).
__global__ __launch_bounds__(256) void k_prep(const float* __restrict__ nv1,
                                              const float* __restrict__ nv2,
                                              const float* __restrict__ W,
                                              short* __restrict__ Mfrag) {
    __shared__ float Al[NN * 129];
    __shared__ float cl[2][NN];
    const int t = threadIdx.x, w = t >> 6, l = t & 63;

    // ---- phase A: 32 passes, one row per wave per pass ----
    for (int pass = 0; pass < 32; ++pass) {
        int r = pass * 4 + w;
        float s0 = 0.f, s1 = 0.f;
#pragma unroll
        for (int k = 0; k < ND; ++k) {
            float a = nv1[r * ND + k];
            s0 = fmaf(a, nv2[k * NN + l], s0);
            s1 = fmaf(a, nv2[k * NN + 64 + l], s1);
        }
        s0 = fmaxf(s0, 0.f);
        s1 = fmaxf(s1, 0.f);
        float m = fmaxf(s0, s1);
#pragma unroll
        for (int d = 32; d; d >>= 1) m = fmaxf(m, __shfl_xor(m, d));
        float e0 = expf(s0 - m), e1 = expf(s1 - m);
        float ss = e0 + e1;
#pragma unroll
        for (int d = 32; d; d >>= 1) ss += __shfl_xor(ss, d);
        float p0 = e0 / ss, p1 = e1 / ss;
        float ps = p0 + p1;
#pragma unroll
        for (int d = 32; d; d >>= 1) ps += __shfl_xor(ps, d);
        float ra = 1.f / (ps + 1.f);
        Al[r * 129 + l]      = (p0 + (l == r ? 1.f : 0.f)) * ra;
        Al[r * 129 + 64 + l] = (p1 + ((l + 64) == r ? 1.f : 0.f)) * ra;
    }
    __syncthreads();

    const int o_sub = t >> 7, u = t & 127;
    const int o = blockIdx.x * 2 + o_sub;

    // ---- phase t/c ----
    float tt = 0.f;
    for (int w2 = 0; w2 < NN; ++w2)
        tt = fmaf(W[o * 384 + 256 + w2], Al[w2 * 129 + u], tt);
    cl[o_sub][u] = fmaf(0.25f, tt,
                        fmaf(0.5f, W[o * 384 + 128 + u], 0.25f * W[o * 384 + 256 + u]));
    __syncthreads();

    // ---- phase M ----
    float m = W[o * 384 + u] + 0.5f * (W[o * 384 + 128 + u] + W[o * 384 + 256 + u]);
    const float* cp = cl[o_sub];
    for (int w2 = 0; w2 < NN; ++w2)
        m = fmaf(cp[w2], Al[w2 * 129 + u], m);

    int kk = u >> 4, hi2 = (u >> 3) & 1, e = u & 7;
    int ti = (o >> 5) * 64 + hi2 * 32 + (o & 31);
    __hip_bfloat16 hb = __float2bfloat16(m);
    Mfrag[kk * 2048 + ti * 8 + e] = *(short*)&hb;
}

// ---------------------------------------------------------------------------
// Main: one block per (b,c). 4 waves; wave w owns v rows [w*32, w*32+32),
// 64 pixels as two 32x32 MFMA tiles, K=128 (8 x mfma_f32_32x32x16_bf16 each).
__global__ __launch_bounds__(256, 4) void k_main(const float* __restrict__ x,
                                                 const short* __restrict__ Mfrag,
                                                 const float* __restrict__ cb,
                                                 const float* __restrict__ lnw,
                                                 const float* __restrict__ lnb,
                                                 float* __restrict__ out) {
    __shared__ short xsT[LL * NN];            // [p][k] bf16, byte^=((p&15)<<4)
    __shared__ __hip_bfloat16 yt[LL * 132];   // [p][v], row stride 132 (264 B)
    __shared__ float cbs[NN], lnws[NN], lnbs[NN];
    __shared__ float mu[LL], rsg[LL];

    const int t = threadIdx.x;
    const int c = blockIdx.x, b = blockIdx.y;
    const int w = t >> 6, l = t & 63;

    // ---- A fragments: 8 x bf16x8 = 32 VGPRs ----
    bf16x8 af[8];
#pragma unroll
    for (int kk = 0; kk < 8; ++kk)
        af[kk] = *(const bf16x8*)(Mfrag + kk * 2048 + t * 8);

    // ---- stage x -> xsT (transpose + bf16 pack + XOR swizzle) ----
    const float* xsrc = x + (size_t)b * NN * GDIM + (size_t)c * LL;
    char* xbb = (char*)xsT;
#pragma unroll
    for (int q = 0; q < 2; ++q) {
        int j = t + q * 256;
        int pq = j & 15, vq = j >> 4;        // vq 0..31 (x4 rows), pq 0..15 (x4 px)
        int pb = pq * 4;
        const float* rp = xsrc + (size_t)(vq * 4) * GDIM + pb;
        float4 r0 = *(const float4*)(rp);
        float4 r1 = *(const float4*)(rp + GDIM);
        float4 r2 = *(const float4*)(rp + 2 * GDIM);
        float4 r3 = *(const float4*)(rp + 3 * GDIM);
        float c0[4] = {r0.x, r0.y, r0.z, r0.w};
        float c1[4] = {r1.x, r1.y, r1.z, r1.w};
        float c2[4] = {r2.x, r2.y, r2.z, r2.w};
        float c3[4] = {r3.x, r3.y, r3.z, r3.w};
#pragma unroll
        for (int jj = 0; jj < 4; ++jj) {
            int p = pb + jj;
            uint2 wv;
            wv.x = pk2(c0[jj], c1[jj]);
            wv.y = pk2(c2[jj], c3[jj]);
            *(uint2*)(xbb + p * 256 + ((vq * 8) ^ ((p & 15) << 4))) = wv;
        }
    }
    if (t < NN) { cbs[t] = cb[t]; lnws[t] = lnw[t]; lnbs[t] = lnb[t]; }
    __syncthreads();

    // ---- MFMA K-loop ----
    const int hi = l >> 5;
    const int pc0 = l & 31, pc1 = 32 + (l & 31);
    const int sw = (l & 15) << 4;
    const char* xrb = (const char*)xsT;

    f32x16 acc0, acc1;
#pragma unroll
    for (int i = 0; i < 16; ++i) { acc0[i] = 0.f; acc1[i] = 0.f; }

#pragma unroll
    for (int kk = 0; kk < 8; ++kk) {
        int kb = kk * 32 + hi * 16;
        bf16x8 b0 = *(const bf16x8*)(xrb + pc0 * 256 + (kb ^ sw));
        bf16x8 b1 = *(const bf16x8*)(xrb + pc1 * 256 + (kb ^ sw));
        acc0 = __builtin_amdgcn_mfma_f32_32x32x16_bf16(af[kk], b0, acc0, 0, 0, 0);
        acc1 = __builtin_amdgcn_mfma_f32_32x32x16_bf16(af[kk], b1, acc1, 0, 0, 0);
    }

    // ---- epilogue: residual from xsT (bf16), bias + fast GELU, pack to yt ----
    // D layout: col = lane&31, row = (r&3) + 8*(r>>2) + 4*(lane>>5)
    const int vh = hi * 4;
    char* ytb = (char*)yt;
#pragma unroll
    for (int g = 0; g < 4; ++g) {
        const int vb = w * 32 + g * 8 + vh;
        const float cb0 = cbs[vb], cb1 = cbs[vb + 1], cb2 = cbs[vb + 2], cb3 = cbs[vb + 3];
        {
            uint2 xw = *(const uint2*)(xrb + pc0 * 256 + ((vb * 2) ^ sw));
            float y0 = bl(xw.x) + gelu(acc0[4 * g + 0] + cb0);
            float y1 = bh(xw.x) + gelu(acc0[4 * g + 1] + cb1);
            float y2 = bl(xw.y) + gelu(acc0[4 * g + 2] + cb2);
            float y3 = bh(xw.y) + gelu(acc0[4 * g + 3] + cb3);
            uint2 yw; yw.x = pk2(y0, y1); yw.y = pk2(y2, y3);
            *(uint2*)(ytb + pc0 * 264 + vb * 2) = yw;
        }
        {
            uint2 xw = *(const uint2*)(xrb + pc1 * 256 + ((vb * 2) ^ sw));
            float y0 = bl(xw.x) + gelu(acc1[4 * g + 0] + cb0);
            float y1 = bh(xw.x) + gelu(acc1[4 * g + 1] + cb1);
            float y2 = bl(xw.y) + gelu(acc1[4 * g + 2] + cb2);
            float y3 = bh(xw.y) + gelu(acc1[4 * g + 3] + cb3);
            uint2 yw; yw.x = pk2(y0, y1); yw.y = pk2(y2, y3);
            *(uint2*)(ytb + pc1 * 264 + vb * 2) = yw;
        }
    }
    __syncthreads();

    // ---- LayerNorm stats: wave w owns pixels w*16..+15, 4 lanes/pixel ----
    {
        int p = w * 16 + (l >> 2), sub = l & 3;
        const uint2* yr = (const uint2*)(ytb + p * 264 + sub * 64);
        float s = 0.f, s2 = 0.f;
#pragma unroll
        for (int j = 0; j < 8; ++j) {
            uint2 u = yr[j];
            float a0 = bl(u.x), a1 = bh(u.x), a2 = bl(u.y), a3 = bh(u.y);
            s += (a0 + a1) + (a2 + a3);
            s2 = fmaf(a0, a0, fmaf(a1, a1, fmaf(a2, a2, fmaf(a3, a3, s2))));
        }
        s  += __shfl_xor(s, 1);  s  += __shfl_xor(s, 2);
        s2 += __shfl_xor(s2, 1); s2 += __shfl_xor(s2, 2);
        if (sub == 0) {
            float mean = s * (1.f / NN);
            float var  = s2 * (1.f / NN) - mean * mean;
            mu[p]  = mean;
            rsg[p] = rsqrtf(var + 1e-5f);
        }
    }
    __syncthreads();

    // ---- normalize + write out[b, c*64+p, v] as float4 ----
    {
        float* op = out + ((size_t)b * GDIM + (size_t)c * LL) * NN;
#pragma unroll
        for (int kk = 0; kk < 8; ++kk) {
            int i = t + kk * 256;             // 2048 float4 slots
            int p = i >> 5, v4 = (i & 31) * 4;
            uint2 u = *(const uint2*)(ytb + p * 264 + v4 * 2);
            float4 lw = *(const float4*)(lnws + v4);
            float4 lb = *(const float4*)(lnbs + v4);
            float mm = mu[p], rr = rsg[p];
            float4 o4;
            o4.x = (bl(u.x) - mm) * rr * lw.x + lb.x;
            o4.y = (bh(u.x) - mm) * rr * lw.y + lb.y;
            o4.z = (bl(u.y) - mm) * rr * lw.z + lb.z;
            o4.w = (bh(u.y) - mm) * rr * lw.w + lb.w;
            *(float4*)(op + p * NN + v4) = o4;
        }
    }
}

// ---------------------------------------------------------------------------
extern "C" void kernel_launch(void* const* d_in, const int* in_sizes, int n_in,
                              void* d_out, int out_size, void* d_ws, size_t ws_size,
                              hipStream_t stream) {
    const float* x   = (const float*)d_in[0];
    const float* nv1 = (const float*)d_in[1];
    const float* nv2 = (const float*)d_in[2];
    const float* cw  = (const float*)d_in[3];
    const float* cb  = (const float*)d_in[4];
    const float* lnw = (const float*)d_in[5];
    const float* lnb = (const float*)d_in[6];
    float* out = (float*)d_out;
    short* Mfrag = (short*)d_ws;   // 32 KB in d_ws

    k_prep<<<64, 256, 0, stream>>>(nv1, nv2, cw, Mfrag);
    k_main<<<dim3(CC, BB), 256, 0, stream>>>(x, Mfrag, cb, lnw, lnb, out);
}

// Round 5
// 38.203 us; speedup vs baseline: 1.8673x; 1.8673x over previous
//
#include <hip/hip_runtime.h>
#include <hip/hip_bf16.h>
#include <math.h>

#define NN 128   // nodes (C_OUT)
#define ND 40    // node_dim
#define BB 32    // batch
#define CC 64    // channels
#define LL 64    // length
#define GDIM (CC*LL)  // 4096

typedef __attribute__((ext_vector_type(8))) short bf16x8;
typedef __attribute__((ext_vector_type(16))) float f32x16;

static __device__ __forceinline__ unsigned pk2(float a, float b) {
    __hip_bfloat162 h;
    h.x = __float2bfloat16(a);
    h.y = __float2bfloat16(b);
    return *(unsigned*)&h;
}
static __device__ __forceinline__ float bl(unsigned u) { return __uint_as_float(u << 16); }
static __device__ __forceinline__ float bh(unsigned u) { return __uint_as_float(u & 0xffff0000u); }

// tanh-form GELU via sigmoid; overflow-safe at both tails.
static __device__ __forceinline__ float gelu(float v) {
    float v2 = v * v;
    float zn = v * fmaf(v2, -0.07135481627f, -1.5957691216f);
    float e  = __expf(zn);
    return v * __builtin_amdgcn_rcpf(1.f + e);
}

// ---------------------------------------------------------------------------
// K1: fused relu(nv1@nv2) + row softmax + self-loop + row-normalize -> A.
// 64 blocks x 128 threads, one wave per row.
__global__ __launch_bounds__(128) void k_adj(const float* __restrict__ nv1,
                                             const float* __restrict__ nv2,
                                             float* __restrict__ A) {
    int t = threadIdx.x;
    int r = blockIdx.x * 2 + (t >> 6);
    int l = t & 63;
    float s0 = 0.f, s1 = 0.f;
#pragma unroll
    for (int k = 0; k < ND; ++k) {
        float a = nv1[r * ND + k];
        s0 = fmaf(a, nv2[k * NN + l], s0);
        s1 = fmaf(a, nv2[k * NN + 64 + l], s1);
    }
    s0 = fmaxf(s0, 0.f);
    s1 = fmaxf(s1, 0.f);
    float m = fmaxf(s0, s1);
#pragma unroll
    for (int d = 32; d; d >>= 1) m = fmaxf(m, __shfl_xor(m, d));
    float e0 = expf(s0 - m), e1 = expf(s1 - m);
    float ss = e0 + e1;
#pragma unroll
    for (int d = 32; d; d >>= 1) ss += __shfl_xor(ss, d);
    float p0 = e0 / ss, p1 = e1 / ss;
    float ps = p0 + p1;
#pragma unroll
    for (int d = 32; d; d >>= 1) ps += __shfl_xor(ps, d);
    float ra = 1.f / (ps + 1.f);
    A[r * NN + l]      = (p0 + (l == r ? 1.f : 0.f)) * ra;
    A[r * NN + 64 + l] = (p1 + ((l + 64) == r ? 1.f : 0.f)) * ra;
}

// ---------------------------------------------------------------------------
// K2: one block per output row o (128 blocks x 256 threads).
//   t[u] = sum_w W2[o,w] A[w,u];  c[w] = 0.5 W1 + 0.25 W2 + 0.25 t
//   M[o,v] = (W0+.5W1+.5W2)[o,v] + sum_w c[w] A[w,v]  -> Mfrag (bf16,
//   MFMA-A-fragment layout for k_main: same mapping as previous rounds).
__global__ __launch_bounds__(256) void k_mm(const float* __restrict__ A,
                                            const float* __restrict__ W,
                                            short* __restrict__ Mfrag) {
    __shared__ float Al[NN * 132];   // row stride 132 (16B-aligned rows)
    __shared__ float red[256];
    __shared__ float cl[NN];
    const int t = threadIdx.x;
    const int o = blockIdx.x;

    // stage A: 16384 floats, 16 float4 per thread
    {
        const float4* As = (const float4*)A;
#pragma unroll
        for (int q = 0; q < 16; ++q) {
            int i = t + q * 256;
            int r = i >> 5, c4 = (i & 31) * 4;
            *(float4*)(Al + r * 132 + c4) = As[i];
        }
    }
    __syncthreads();

    const int u = t & 127, h = t >> 7;

    // phase t
    float tp = 0.f;
    const float* w2p = W + o * 384 + 256 + h * 64;
#pragma unroll 8
    for (int w2 = 0; w2 < 64; ++w2)
        tp = fmaf(w2p[w2], Al[(h * 64 + w2) * 132 + u], tp);
    red[t] = tp;
    __syncthreads();
    if (t < NN) {
        float tt = red[t] + red[t + 128];
        cl[t] = fmaf(0.25f, tt, fmaf(0.5f, W[o * 384 + 128 + t],
                                     0.25f * W[o * 384 + 256 + t]));
    }
    __syncthreads();

    // phase M
    float mp = 0.f;
#pragma unroll 8
    for (int w2 = 0; w2 < 64; ++w2)
        mp = fmaf(cl[h * 64 + w2], Al[(h * 64 + w2) * 132 + u], mp);
    red[t] = mp;
    __syncthreads();
    if (t < NN) {
        float m = W[o * 384 + t] + 0.5f * (W[o * 384 + 128 + t] + W[o * 384 + 256 + t])
                + red[t] + red[t + 128];
        int kk = t >> 4, hi2 = (t >> 3) & 1, e = t & 7;
        int ti = (o >> 5) * 64 + hi2 * 32 + (o & 31);
        __hip_bfloat16 hb = __float2bfloat16(m);
        Mfrag[kk * 2048 + ti * 8 + e] = *(short*)&hb;
    }
}

// ---------------------------------------------------------------------------
// Main: one block per (b,c). 4 waves; wave w owns v rows [w*32, w*32+32),
// 64 pixels as two 32x32 MFMA tiles, K=128. y written IN PLACE into xsT.
__global__ __launch_bounds__(256, 5) void k_main(const float* __restrict__ x,
                                                 const short* __restrict__ Mfrag,
                                                 const float* __restrict__ cb,
                                                 const float* __restrict__ lnw,
                                                 const float* __restrict__ lnb,
                                                 float* __restrict__ out) {
    __shared__ short xsT[LL * NN];            // [p][k] bf16, byte^=((p&15)<<4)
    __shared__ float cbs[NN], lnws[NN], lnbs[NN];
    __shared__ float mu[LL], rsg[LL];

    const int t = threadIdx.x;
    const int c = blockIdx.x, b = blockIdx.y;
    const int w = t >> 6, l = t & 63;

    // ---- A fragments: 8 x bf16x8 = 32 VGPRs ----
    bf16x8 af[8];
#pragma unroll
    for (int kk = 0; kk < 8; ++kk)
        af[kk] = *(const bf16x8*)(Mfrag + kk * 2048 + t * 8);

    // ---- stage x -> xsT (transpose + bf16 pack + XOR swizzle) ----
    const float* xsrc = x + (size_t)b * NN * GDIM + (size_t)c * LL;
    char* xbb = (char*)xsT;
#pragma unroll
    for (int q = 0; q < 2; ++q) {
        int j = t + q * 256;
        int pq = j & 15, vq = j >> 4;
        int pb = pq * 4;
        const float* rp = xsrc + (size_t)(vq * 4) * GDIM + pb;
        float4 r0 = *(const float4*)(rp);
        float4 r1 = *(const float4*)(rp + GDIM);
        float4 r2 = *(const float4*)(rp + 2 * GDIM);
        float4 r3 = *(const float4*)(rp + 3 * GDIM);
        float c0[4] = {r0.x, r0.y, r0.z, r0.w};
        float c1[4] = {r1.x, r1.y, r1.z, r1.w};
        float c2[4] = {r2.x, r2.y, r2.z, r2.w};
        float c3[4] = {r3.x, r3.y, r3.z, r3.w};
#pragma unroll
        for (int jj = 0; jj < 4; ++jj) {
            int p = pb + jj;
            uint2 wv;
            wv.x = pk2(c0[jj], c1[jj]);
            wv.y = pk2(c2[jj], c3[jj]);
            *(uint2*)(xbb + p * 256 + ((vq * 8) ^ ((p & 15) << 4))) = wv;
        }
    }
    if (t < NN) { cbs[t] = cb[t]; lnws[t] = lnw[t]; lnbs[t] = lnb[t]; }
    __syncthreads();

    // ---- MFMA K-loop ----
    const int hi = l >> 5;
    const int pc0 = l & 31, pc1 = 32 + (l & 31);
    const int sw = (l & 15) << 4;
    const char* xrb = (const char*)xsT;

    f32x16 acc0, acc1;
#pragma unroll
    for (int i = 0; i < 16; ++i) { acc0[i] = 0.f; acc1[i] = 0.f; }

#pragma unroll
    for (int kk = 0; kk < 8; ++kk) {
        int kb = kk * 32 + hi * 16;
        bf16x8 b0 = *(const bf16x8*)(xrb + pc0 * 256 + (kb ^ sw));
        bf16x8 b1 = *(const bf16x8*)(xrb + pc1 * 256 + (kb ^ sw));
        acc0 = __builtin_amdgcn_mfma_f32_32x32x16_bf16(af[kk], b0, acc0, 0, 0, 0);
        acc1 = __builtin_amdgcn_mfma_f32_32x32x16_bf16(af[kk], b1, acc1, 0, 0, 0);
    }
    __syncthreads();   // all waves done reading xsT as B before in-place writes

    // ---- epilogue: residual from xsT, bias + GELU, write y back IN PLACE ----
    // D layout: col = lane&31, row = (r&3) + 8*(r>>2) + 4*(lane>>5)
    const int vh = hi * 4;
    char* ywb = (char*)xsT;
#pragma unroll
    for (int g = 0; g < 4; ++g) {
        const int vb = w * 32 + g * 8 + vh;
        const float cb0 = cbs[vb], cb1 = cbs[vb + 1], cb2 = cbs[vb + 2], cb3 = cbs[vb + 3];
        {
            char* sp = ywb + pc0 * 256 + ((vb * 2) ^ sw);
            uint2 xw = *(const uint2*)sp;
            float y0 = bl(xw.x) + gelu(acc0[4 * g + 0] + cb0);
            float y1 = bh(xw.x) + gelu(acc0[4 * g + 1] + cb1);
            float y2 = bl(xw.y) + gelu(acc0[4 * g + 2] + cb2);
            float y3 = bh(xw.y) + gelu(acc0[4 * g + 3] + cb3);
            uint2 yw; yw.x = pk2(y0, y1); yw.y = pk2(y2, y3);
            *(uint2*)sp = yw;
        }
        {
            char* sp = ywb + pc1 * 256 + ((vb * 2) ^ sw);
            uint2 xw = *(const uint2*)sp;
            float y0 = bl(xw.x) + gelu(acc1[4 * g + 0] + cb0);
            float y1 = bh(xw.x) + gelu(acc1[4 * g + 1] + cb1);
            float y2 = bl(xw.y) + gelu(acc1[4 * g + 2] + cb2);
            float y3 = bh(xw.y) + gelu(acc1[4 * g + 3] + cb3);
            uint2 yw; yw.x = pk2(y0, y1); yw.y = pk2(y2, y3);
            *(uint2*)sp = yw;
        }
    }
    __syncthreads();

    // ---- LayerNorm stats: wave w owns pixels w*16..+15, 4 lanes/pixel.
    // XOR swizzle is a within-row bijection -> summing the permuted row is exact.
    {
        int p = w * 16 + (l >> 2), sub = l & 3;
        int mask = (p & 15) << 4;
        const char* base = xrb + p * 256;
        float s = 0.f, s2 = 0.f;
#pragma unroll
        for (int j = 0; j < 8; ++j) {
            uint2 u = *(const uint2*)(base + ((sub * 64 + j * 8) ^ mask));
            float a0 = bl(u.x), a1 = bh(u.x), a2 = bl(u.y), a3 = bh(u.y);
            s += (a0 + a1) + (a2 + a3);
            s2 = fmaf(a0, a0, fmaf(a1, a1, fmaf(a2, a2, fmaf(a3, a3, s2))));
        }
        s  += __shfl_xor(s, 1);  s  += __shfl_xor(s, 2);
        s2 += __shfl_xor(s2, 1); s2 += __shfl_xor(s2, 2);
        if (sub == 0) {
            float mean = s * (1.f / NN);
            float var  = s2 * (1.f / NN) - mean * mean;
            mu[p]  = mean;
            rsg[p] = rsqrtf(var + 1e-5f);
        }
    }
    __syncthreads();

    // ---- normalize + write out[b, c*64+p, v] as float4 ----
    {
        float* op = out + ((size_t)b * GDIM + (size_t)c * LL) * NN;
#pragma unroll
        for (int kk = 0; kk < 8; ++kk) {
            int i = t + kk * 256;
            int p = i >> 5, v4 = (i & 31) * 4;
            int mask = (p & 15) << 4;
            uint2 u = *(const uint2*)(xrb + p * 256 + ((v4 * 2) ^ mask));
            float4 lw = *(const float4*)(lnws + v4);
            float4 lb = *(const float4*)(lnbs + v4);
            float mm = mu[p], rr = rsg[p];
            float4 o4;
            o4.x = (bl(u.x) - mm) * rr * lw.x + lb.x;
            o4.y = (bh(u.x) - mm) * rr * lw.y + lb.y;
            o4.z = (bl(u.y) - mm) * rr * lw.z + lb.z;
            o4.w = (bh(u.y) - mm) * rr * lw.w + lb.w;
            *(float4*)(op + p * NN + v4) = o4;
        }
    }
}

// ---------------------------------------------------------------------------
extern "C" void kernel_launch(void* const* d_in, const int* in_sizes, int n_in,
                              void* d_out, int out_size, void* d_ws, size_t ws_size,
                              hipStream_t stream) {
    const float* x   = (const float*)d_in[0];
    const float* nv1 = (const float*)d_in[1];
    const float* nv2 = (const float*)d_in[2];
    const float* cw  = (const float*)d_in[3];
    const float* cb  = (const float*)d_in[4];
    const float* lnw = (const float*)d_in[5];
    const float* lnb = (const float*)d_in[6];
    float* out = (float*)d_out;

    short* Mfrag = (short*)d_ws;                       // 32 KB
    float* A     = (float*)((char*)d_ws + 32768);      // 64 KB

    k_adj<<<64, 128, 0, stream>>>(nv1, nv2, A);
    k_mm <<<NN, 256, 0, stream>>>(A, cw, Mfrag);
    k_main<<<dim3(CC, BB), 256, 0, stream>>>(x, Mfrag, cb, lnw, lnb, out);
}